// Round 2
// baseline (186.851 us; speedup 1.0000x reference)
//
#include <hip/hip_runtime.h>

#define DIN 768

__device__ __forceinline__ int swz(int i) { return i ^ ((i >> 4) & 31); }

// Composite gather map of the CNOT ring CNOT(0,1)..CNOT(9,0): Final[i] = In[cnotL(i)]
__device__ __forceinline__ int cnotL(int i) {
  const int b9 = (i >> 9) & 1;
  const int b8 = (i >> 8) & 1;
  const int b0 = i & 1;
  return ((i ^ (i >> 1)) & 0xFF) | ((b8 ^ b9 ^ b0) << 8) | ((b9 ^ b0) << 9);
}

template<int RB>
__device__ __forceinline__ void ry_reg_real(float (&sr)[16], float c, float s) {
#pragma unroll
  for (int r = 0; r < 16; ++r) {
    if (!(r & (1 << RB))) {
      const int r1 = r | (1 << RB);
      const float a0 = sr[r], a1 = sr[r1];
      sr[r]  = c * a0 - s * a1;
      sr[r1] = s * a0 + c * a1;
    }
  }
}

template<int RB>
__device__ __forceinline__ void ry_reg(float (&sr)[16], float (&si)[16], float c, float s) {
#pragma unroll
  for (int r = 0; r < 16; ++r) {
    if (!(r & (1 << RB))) {
      const int r1 = r | (1 << RB);
      float a0 = sr[r], a1 = sr[r1];
      sr[r]  = c * a0 - s * a1;
      sr[r1] = s * a0 + c * a1;
      a0 = si[r]; a1 = si[r1];
      si[r]  = c * a0 - s * a1;
      si[r1] = s * a0 + c * a1;
    }
  }
}

template<int MASK>
__device__ __forceinline__ void ry_shfl_real(int lane, float (&sr)[16], float c, float s) {
  const float ss = (lane & MASK) ? s : -s;
#pragma unroll
  for (int r = 0; r < 16; ++r) {
    const float p = __shfl_xor(sr[r], MASK);
    sr[r] = fmaf(ss, p, c * sr[r]);
  }
}

template<int MASK>
__device__ __forceinline__ void ry_shfl(int lane, float (&sr)[16], float (&si)[16], float c, float s) {
  const float ss = (lane & MASK) ? s : -s;
#pragma unroll
  for (int r = 0; r < 16; ++r) {
    const float pr = __shfl_xor(sr[r], MASK);
    const float pi = __shfl_xor(si[r], MASK);
    sr[r] = fmaf(ss, pr, c * sr[r]);
    si[r] = fmaf(ss, pi, c * si[r]);
  }
}

// RZ on all 10 qubits, layout B (i = (r<<6)|lane). off = weight offset of rz block.
__device__ __forceinline__ void rz_apply(int lane, const float* __restrict__ w, int off,
                                         float (&sr)[16], float (&si)[16]) {
  float phiL = 0.f;
#pragma unroll
  for (int j = 0; j < 6; ++j) {               // lane bit j <-> qubit 9-j
    const float h = 0.5f * w[off + 9 - j];
    phiL += ((lane >> j) & 1) ? h : -h;
  }
  const float h0 = 0.5f * w[off + 0];          // r bit 3 <-> qubit 0
  const float h1 = 0.5f * w[off + 1];
  const float h2 = 0.5f * w[off + 2];
  const float h3 = 0.5f * w[off + 3];
  const float base = phiL - h0 - h1 - h2 - h3;
#pragma unroll
  for (int r = 0; r < 16; ++r) {
    float ang = base;
    if (r & 8) ang += 2.f * h0;
    if (r & 4) ang += 2.f * h1;
    if (r & 2) ang += 2.f * h2;
    if (r & 1) ang += 2.f * h3;
    float sn, cn;
    __sincosf(ang, &sn, &cn);
    const float re = sr[r], im = si[r];
    sr[r] = re * cn - im * sn;
    si[r] = fmaf(re, sn, im * cn);
  }
}

template<int RB, int Q>
__device__ __forceinline__ void xy_reg(const float (&sr)[16], const float (&si)[16], float (&acc)[18]) {
#pragma unroll
  for (int r = 0; r < 16; ++r) {
    if (!(r & (1 << RB))) {
      const int r1 = r | (1 << RB);
      acc[Q]     += 2.f * (sr[r] * sr[r1] + si[r] * si[r1]);
      acc[Q + 6] += 2.f * (sr[r] * si[r1] - si[r] * sr[r1]);
    }
  }
}

template<int MASK, int Q>
__device__ __forceinline__ void xy_shfl(int lane, const float (&sr)[16], const float (&si)[16], float (&acc)[18]) {
  const float sgn = (lane & MASK) ? -1.f : 1.f;
#pragma unroll
  for (int r = 0; r < 16; ++r) {
    const float pr = __shfl_xor(sr[r], MASK);
    const float pi = __shfl_xor(si[r], MASK);
    acc[Q]     += sr[r] * pr + si[r] * pi;       // double-counted pair -> net 2x
    acc[Q + 6] += sgn * (sr[r] * pi - si[r] * pr);
  }
}

__global__ __launch_bounds__(64) void qae_kernel(const float* __restrict__ x,
                                                 const float* __restrict__ w,
                                                 float* __restrict__ out) {
  __shared__ float2 st[1024];
  __shared__ float2 tab[70];   // (cos, sin) of half-angles; [60..69] = combined RY round

  const int lane = threadIdx.x;
  const int b = blockIdx.x;

  if (lane < 60) {             // tab[0..59]: per-gate half-angle (cos, sin)
    float s, c;
    __sincosf(0.5f * w[lane], &s, &c);
    tab[lane] = make_float2(c, s);
  }
  if (lane < 10) {             // tab[60..69]: RY_b(layer1) + RY_c(layer2) folded
    float s, c;                // (was lanes 60..69 before -- lanes 64..69 don't exist!)
    __sincosf(0.5f * (w[20 + lane] + w[30 + lane]), &s, &c);
    tab[60 + lane] = make_float2(c, s);
  }
  __syncthreads();

  // Load row in layout A: amplitude i = (lane<<4)|r ; i >= 768 are zero pad.
  float sr[16], si[16];
  float sumsq = 0.f;
  const float* xb = x + (size_t)b * DIN;
#pragma unroll
  for (int k = 0; k < 4; ++k) {
    const int idx = lane * 16 + 4 * k;
    float4 v = make_float4(0.f, 0.f, 0.f, 0.f);
    if (idx < DIN) v = *reinterpret_cast<const float4*>(xb + idx);
    sr[4*k+0] = v.x; sr[4*k+1] = v.y; sr[4*k+2] = v.z; sr[4*k+3] = v.w;
    sumsq += v.x*v.x; sumsq += v.y*v.y; sumsq += v.z*v.z; sumsq += v.w*v.w;
  }
#pragma unroll
  for (int m = 32; m >= 1; m >>= 1) sumsq += __shfl_xor(sumsq, m);
  const float inv_n2 = 1.f / fmaxf(sumsq, 1e-16f);   // deferred normalization (quadratic outputs)

  float2 cs;
  // ================= layer 1 : RY round (w[0..9]) — state is REAL =================
  cs = tab[6]; ry_reg_real<3>(sr, cs.x, cs.y);       // A: qubit6 -> r bit 3
  cs = tab[7]; ry_reg_real<2>(sr, cs.x, cs.y);
  cs = tab[8]; ry_reg_real<1>(sr, cs.x, cs.y);
  cs = tab[9]; ry_reg_real<0>(sr, cs.x, cs.y);
  cs = tab[4]; ry_shfl_real<2>(lane, sr, cs.x, cs.y); // A: qubit4 -> lane bit 1
  cs = tab[5]; ry_shfl_real<1>(lane, sr, cs.x, cs.y); // A: qubit5 -> lane bit 0

  { // T1: A->B transpose (real)
    float* stf = reinterpret_cast<float*>(st);
    __syncthreads();
#pragma unroll
    for (int r = 0; r < 16; ++r) { const int i = (lane << 4) | r; stf[swz(i)] = sr[r]; }
    __syncthreads();
#pragma unroll
    for (int r = 0; r < 16; ++r) { const int i = (r << 6) | lane; sr[r] = stf[swz(i)]; }
  }
  cs = tab[0]; ry_reg_real<3>(sr, cs.x, cs.y);       // B: qubit0 -> r bit 3
  cs = tab[1]; ry_reg_real<2>(sr, cs.x, cs.y);
  cs = tab[2]; ry_reg_real<1>(sr, cs.x, cs.y);
  cs = tab[3]; ry_reg_real<0>(sr, cs.x, cs.y);

  { // RZ layer 1 (w[10..19]) : real -> complex
    float phiL = 0.f;
#pragma unroll
    for (int j = 0; j < 6; ++j) {
      const float h = 0.5f * w[10 + 9 - j];
      phiL += ((lane >> j) & 1) ? h : -h;
    }
    const float h0 = 0.5f*w[10], h1 = 0.5f*w[11], h2 = 0.5f*w[12], h3 = 0.5f*w[13];
    const float base = phiL - h0 - h1 - h2 - h3;
#pragma unroll
    for (int r = 0; r < 16; ++r) {
      float ang = base;
      if (r & 8) ang += 2.f*h0;
      if (r & 4) ang += 2.f*h1;
      if (r & 2) ang += 2.f*h2;
      if (r & 1) ang += 2.f*h3;
      float sn, cn;
      __sincosf(ang, &sn, &cn);
      si[r] = sr[r] * sn;
      sr[r] = sr[r] * cn;
    }
  }

  // T2: CNOT ring (layer1) fused into B->A transpose
  __syncthreads();
#pragma unroll
  for (int r = 0; r < 16; ++r) { const int i = (r << 6) | lane; st[swz(i)] = make_float2(sr[r], si[r]); }
  __syncthreads();
#pragma unroll
  for (int r = 0; r < 16; ++r) { const int i = (lane << 4) | r; const float2 v = st[swz(cnotL(i))]; sr[r] = v.x; si[r] = v.y; }

  // ===== combined RY round: layer1 RY_b + layer2 RY_c (tab[60+q]) =====
  cs = tab[66]; ry_reg<3>(sr, si, cs.x, cs.y);
  cs = tab[67]; ry_reg<2>(sr, si, cs.x, cs.y);
  cs = tab[68]; ry_reg<1>(sr, si, cs.x, cs.y);
  cs = tab[69]; ry_reg<0>(sr, si, cs.x, cs.y);
  cs = tab[64]; ry_shfl<2>(lane, sr, si, cs.x, cs.y);
  cs = tab[65]; ry_shfl<1>(lane, sr, si, cs.x, cs.y);

  // T3: A->B
  __syncthreads();
#pragma unroll
  for (int r = 0; r < 16; ++r) { const int i = (lane << 4) | r; st[swz(i)] = make_float2(sr[r], si[r]); }
  __syncthreads();
#pragma unroll
  for (int r = 0; r < 16; ++r) { const int i = (r << 6) | lane; const float2 v = st[swz(i)]; sr[r] = v.x; si[r] = v.y; }

  cs = tab[60]; ry_reg<3>(sr, si, cs.x, cs.y);
  cs = tab[61]; ry_reg<2>(sr, si, cs.x, cs.y);
  cs = tab[62]; ry_reg<1>(sr, si, cs.x, cs.y);
  cs = tab[63]; ry_reg<0>(sr, si, cs.x, cs.y);

  // RZ layer 2 (w[40..49])
  rz_apply(lane, w, 40, sr, si);

  // T4: CNOT ring (layer2) fused into B->A transpose
  __syncthreads();
#pragma unroll
  for (int r = 0; r < 16; ++r) { const int i = (r << 6) | lane; st[swz(i)] = make_float2(sr[r], si[r]); }
  __syncthreads();
#pragma unroll
  for (int r = 0; r < 16; ++r) { const int i = (lane << 4) | r; const float2 v = st[swz(cnotL(i))]; sr[r] = v.x; si[r] = v.y; }

  // ===== final RY round (w[50..59]) =====
  cs = tab[56]; ry_reg<3>(sr, si, cs.x, cs.y);
  cs = tab[57]; ry_reg<2>(sr, si, cs.x, cs.y);
  cs = tab[58]; ry_reg<1>(sr, si, cs.x, cs.y);
  cs = tab[59]; ry_reg<0>(sr, si, cs.x, cs.y);
  cs = tab[54]; ry_shfl<2>(lane, sr, si, cs.x, cs.y);
  cs = tab[55]; ry_shfl<1>(lane, sr, si, cs.x, cs.y);

  // T5: A->B
  __syncthreads();
#pragma unroll
  for (int r = 0; r < 16; ++r) { const int i = (lane << 4) | r; st[swz(i)] = make_float2(sr[r], si[r]); }
  __syncthreads();
#pragma unroll
  for (int r = 0; r < 16; ++r) { const int i = (r << 6) | lane; const float2 v = st[swz(i)]; sr[r] = v.x; si[r] = v.y; }

  cs = tab[50]; ry_reg<3>(sr, si, cs.x, cs.y);
  cs = tab[51]; ry_reg<2>(sr, si, cs.x, cs.y);
  cs = tab[52]; ry_reg<1>(sr, si, cs.x, cs.y);
  cs = tab[53]; ry_reg<0>(sr, si, cs.x, cs.y);

  // ================= expectation values (layout B) =================
  float acc[18];
#pragma unroll
  for (int k = 0; k < 18; ++k) acc[k] = 0.f;

#pragma unroll
  for (int r = 0; r < 16; ++r) {
    const float p = sr[r]*sr[r] + si[r]*si[r];
    acc[12] += (r & 8) ? -p : p;                 // Z q0
    acc[13] += (r & 4) ? -p : p;                 // Z q1
    acc[14] += (r & 2) ? -p : p;                 // Z q2
    acc[15] += (r & 1) ? -p : p;                 // Z q3
    acc[16] += ((lane >> 5) & 1) ? -p : p;       // Z q4
    acc[17] += ((lane >> 4) & 1) ? -p : p;       // Z q5
  }

  xy_reg<3,0>(sr, si, acc);
  xy_reg<2,1>(sr, si, acc);
  xy_reg<1,2>(sr, si, acc);
  xy_reg<0,3>(sr, si, acc);
  xy_shfl<32,4>(lane, sr, si, acc);
  xy_shfl<16,5>(lane, sr, si, acc);

#pragma unroll
  for (int k = 0; k < 18; ++k) {
#pragma unroll
    for (int m = 32; m >= 1; m >>= 1) acc[k] += __shfl_xor(acc[k], m);
  }

  if (lane == 0) {
    float* ob = out + (size_t)b * 18;
#pragma unroll
    for (int k = 0; k < 18; ++k) ob[k] = acc[k] * inv_n2;
  }
}

extern "C" void kernel_launch(void* const* d_in, const int* in_sizes, int n_in,
                              void* d_out, int out_size, void* d_ws, size_t ws_size,
                              hipStream_t stream) {
  const float* x = (const float*)d_in[0];
  const float* w = (const float*)d_in[1];
  float* out = (float*)d_out;
  const int B = in_sizes[0] / DIN;
  qae_kernel<<<dim3(B), dim3(64), 0, stream>>>(x, w, out);
}